// Round 3
// baseline (128.128 us; speedup 1.0000x reference)
//
#include <hip/hip_runtime.h>
#include <hip/hip_cooperative_groups.h>

#define H     300
#define MID   100
#define NN    1024
#define NP1   1025
#define JST   1088   // padded j-extent of E4 (E4[25][1088][4] floats)

namespace cg = cooperative_groups;

typedef float v2f __attribute__((ext_vector_type(2)));
static __device__ __forceinline__ v2f sp2(float s) { return (v2f){s, s}; }
static __device__ __forceinline__ v2f fma2(v2f a, v2f b, v2f c) {
    return __builtin_elementwise_fma(a, b, c);
}

// 16-lane-row rotate-add via DPP (VALU pipe, no DS traffic).
template <int CTRL>
static __device__ __forceinline__ float row_ror_add(float v) {
    const int s = __builtin_amdgcn_update_dpp(0, __float_as_int(v), CTRL, 0xF, 0xF, true);
    return v + __int_as_float(s);
}
// lane ^ 16 exchange-add (single DS-pipe swizzle, stays within 32-lane group)
static __device__ __forceinline__ float swz_xor16_add(float v) {
    const int s = __builtin_amdgcn_ds_swizzle(__float_as_int(v), 0x401F);
    return v + __int_as_float(s);
}
// full 32-lane-group sum: 1 ds_swizzle + 4 DPP row_ror adds
static __device__ __forceinline__ float red32(float v) {
    v = swz_xor16_add(v);
    v = row_ror_add<0x128>(v);   // row_ror:8
    v = row_ror_add<0x124>(v);   // row_ror:4
    v = row_ror_add<0x122>(v);   // row_ror:2
    v = row_ror_add<0x121>(v);   // row_ror:1
    return v;
}

// ---------------------------------------------------------------------------
// Fused cooperative kernel: 256 blocks x 512 threads (1 block/CU).
// Phase A: block g owns items i0=4g..4g+3. 16 lane-groups of 32; step s gives
// group (m,half) pair p = s*16+grp (200 pairs, 13 steps). Sentence rows live
// in REGISTERS (40/thread). half==0 results -> F-quads straight into LDS
// (s1b global buffer eliminated: phase B of THIS block needs exactly these
// rows). half==1 -> E4[m>>2][j][m&3] = exp2(-s2*log2e) to global (all-to-all).
// grid.sync() provides the cross-XCD-visible barrier (Guideline 16).
// Phase B: identical to round-1/2 main loop (4 rows x 2 cols/thread,
// common-denominator quad-rcp, v_pk f32 pairs).
// ---------------------------------------------------------------------------
__global__ __launch_bounds__(512) void fused_kernel(
    const float* __restrict__ sentence,
    const float* __restrict__ W1,
    const float* __restrict__ b1,
    const float* __restrict__ W2,
    const float* __restrict__ b2,
    const int*   __restrict__ target,
    float* __restrict__ E4,
    float* __restrict__ out)
{
    __shared__ float4 Fq[MID];          // {F_row0..F_row3}[m]  (written phase A)
    __shared__ float4 w4sh[MID / 4];    // W2 m-quads
    __shared__ float  tmp[4][104];      // remainder-column partials per row
    __shared__ float  redl[8];
    __shared__ float4 redm[8];
    __shared__ float4 rede[8];
    __shared__ float  sc4sh[4];
    __shared__ float4 bmax, binv;

    const int tid = threadIdx.x;
    const int i0  = blockIdx.x * 4;
    const float NL  = -1.4426950408889634f;
    const float L2E =  1.4426950408889634f;

    if (blockIdx.x == 0) {
        if (tid == 0) atomicExch(out, 0.0f);                      // loss accumulator (L2-coherent init)
        if (tid < MID)
            E4[(long)((tid >> 2) * JST) * 4 + (tid & 3)] = 1.0f;  // j=0 column
    }
    if (tid >= 128 && tid < 128 + MID / 4) {
        const int p = tid - 128;
        w4sh[p] = make_float4(W2[4 * p], W2[4 * p + 1], W2[4 * p + 2], W2[4 * p + 3]);
    }

    // ======================= phase A =======================
    {
        const int grp = tid >> 5;        // 0..15
        const int hb  = tid & 31;
        const float* sp0 = sentence + (long)(i0 + 0) * H + hb;
        const float* sp1 = sentence + (long)(i0 + 1) * H + hb;
        const float* sp2v = sentence + (long)(i0 + 2) * H + hb;
        const float* sp3 = sentence + (long)(i0 + 3) * H + hb;
        float r0[10], r1[10], r2[10], r3[10];
        #pragma unroll
        for (int k = 0; k < 9; ++k) {
            r0[k] = sp0[32 * k]; r1[k] = sp1[32 * k];
            r2[k] = sp2v[32 * k]; r3[k] = sp3[32 * k];
        }
        const bool tl = hb < 12;                 // tail lanes (h = 288+hb < 300)
        r0[9] = tl ? sp0[288] : 0.f;
        r1[9] = tl ? sp1[288] : 0.f;
        r2[9] = tl ? sp2v[288] : 0.f;
        r3[9] = tl ? sp3[288] : 0.f;
        const int h9 = 288 + (tl ? hb : 0);      // clamped absolute tail index

        for (int s = 0; s < 13; ++s) {
            const int p  = s * 16 + grp;                 // 0..207
            const int pc = p < 200 ? p : 199;            // clamp keeps loads in-bounds
            const int m  = pc >> 1, half = pc & 1;
            const float* wrow = W1 + (long)m * (2 * H) + half * H;

            float a0, a1, a2, a3;
            {
                const float w = wrow[hb];
                a0 = w * r0[0]; a1 = w * r1[0]; a2 = w * r2[0]; a3 = w * r3[0];
            }
            #pragma unroll
            for (int k = 1; k < 9; ++k) {
                const float w = wrow[hb + 32 * k];
                a0 = __builtin_fmaf(w, r0[k], a0);
                a1 = __builtin_fmaf(w, r1[k], a1);
                a2 = __builtin_fmaf(w, r2[k], a2);
                a3 = __builtin_fmaf(w, r3[k], a3);
            }
            {
                const float w = wrow[h9];                // r*[9] zeroed on non-tail lanes
                a0 = __builtin_fmaf(w, r0[9], a0);
                a1 = __builtin_fmaf(w, r1[9], a1);
                a2 = __builtin_fmaf(w, r2[9], a2);
                a3 = __builtin_fmaf(w, r3[9], a3);
            }

            a0 = red32(a0); a1 = red32(a1); a2 = red32(a2); a3 = red32(a3);

            if (hb == 0 && p < 200) {
                if (half == 0) {
                    const float bb = b1[m];
                    Fq[m] = make_float4(
                        __builtin_amdgcn_exp2f((a0 + bb) * NL),
                        __builtin_amdgcn_exp2f((a1 + bb) * NL),
                        __builtin_amdgcn_exp2f((a2 + bb) * NL),
                        __builtin_amdgcn_exp2f((a3 + bb) * NL));
                } else {
                    float* base = E4 + (long)((m >> 2) * JST) * 4 + (m & 3);
                    base[(long)(i0 + 1) * 4] = __builtin_amdgcn_exp2f(a0 * NL);
                    base[(long)(i0 + 2) * 4] = __builtin_amdgcn_exp2f(a1 * NL);
                    base[(long)(i0 + 3) * 4] = __builtin_amdgcn_exp2f(a2 * NL);
                    base[(long)(i0 + 4) * 4] = __builtin_amdgcn_exp2f(a3 * NL);
                }
            }
        }
    }

    cg::this_grid().sync();   // all E4 columns + this block's Fq/w4sh now visible

    // ======================= phase B =======================
    const int lane = tid & 63, wv = tid >> 6;
    const v2f one2 = sp2(1.0f);
    const float b2v = b2[0];

    // coalesced: column j reads float4 at E4 + (p*JST + j)*4
    #define LDXA(p_) (*(const float4*)(E4 + ((long)(p_) * JST + tid) * 4))
    #define LDXB(p_) (*(const float4*)(E4 + ((long)(p_) * JST + tid + 512) * 4))

    v2f acc01a = sp2(0.f), acc23a = sp2(0.f);
    v2f acc01b = sp2(0.f), acc23b = sp2(0.f);

    #define QCOL(X, accLo, accHi)                                             \
        do {                                                                  \
            const v2f e0 = sp2((X).x), e1 = sp2((X).y);                       \
            const v2f e2 = sp2((X).z), e3 = sp2((X).w);                       \
            {   /* rows 0,1 */                                                \
                const v2f A = fma2(e0, (v2f){F0.x, F0.y}, one2);              \
                const v2f B = fma2(e1, (v2f){F1.x, F1.y}, one2);              \
                const v2f C = fma2(e2, (v2f){F2.x, F2.y}, one2);              \
                const v2f D = fma2(e3, (v2f){F3.x, F3.y}, one2);              \
                const v2f AB = A * B, CD = C * D, P = AB * CD;                \
                const v2f R = {__builtin_amdgcn_rcpf(P.x),                    \
                               __builtin_amdgcn_rcpf(P.y)};                   \
                const v2f n1 = fma2(w0, B, w1 * A);                           \
                const v2f n2 = fma2(w2v, D, w3 * C);                          \
                accLo = fma2(fma2(n1, CD, n2 * AB), R, accLo);                \
            }                                                                 \
            {   /* rows 2,3 */                                                \
                const v2f A = fma2(e0, (v2f){F0.z, F0.w}, one2);              \
                const v2f B = fma2(e1, (v2f){F1.z, F1.w}, one2);              \
                const v2f C = fma2(e2, (v2f){F2.z, F2.w}, one2);              \
                const v2f D = fma2(e3, (v2f){F3.z, F3.w}, one2);              \
                const v2f AB = A * B, CD = C * D, P = AB * CD;                \
                const v2f R = {__builtin_amdgcn_rcpf(P.x),                    \
                               __builtin_amdgcn_rcpf(P.y)};                   \
                const v2f n1 = fma2(w0, B, w1 * A);                           \
                const v2f n2 = fma2(w2v, D, w3 * C);                          \
                accHi = fma2(fma2(n1, CD, n2 * AB), R, accHi);                \
            }                                                                 \
        } while (0)

    #define QBODY(p_, XA, XB)                                                 \
        do {                                                                  \
            const float4 F0 = Fq[4 * (p_)];                                   \
            const float4 F1 = Fq[4 * (p_) + 1];                               \
            const float4 F2 = Fq[4 * (p_) + 2];                               \
            const float4 F3 = Fq[4 * (p_) + 3];                               \
            const float4 w  = w4sh[p_];                                       \
            const v2f w0 = sp2(w.x), w1 = sp2(w.y);                           \
            const v2f w2v = sp2(w.z), w3 = sp2(w.w);                          \
            QCOL(XA, acc01a, acc23a);                                         \
            QCOL(XB, acc01b, acc23b);                                         \
        } while (0)

    // 25 m-quads, distance-2 software pipeline on the float4 loads
    float4 xa0 = LDXA(0), xb0 = LDXB(0);
    float4 xa1 = LDXA(1), xb1 = LDXB(1);
    #pragma unroll 2
    for (int p = 0; p < 23; ++p) {
        const float4 xan = LDXA(p + 2), xbn = LDXB(p + 2);
        QBODY(p, xa0, xb0);
        xa0 = xa1; xa1 = xan;
        xb0 = xb1; xb1 = xbn;
    }
    QBODY(23, xa0, xb0);
    QBODY(24, xa1, xb1);

    const float sc0a = acc01a.x + b2v, sc1a = acc01a.y + b2v;
    const float sc2a = acc23a.x + b2v, sc3a = acc23a.y + b2v;
    const float sc0b = acc01b.x + b2v, sc1b = acc01b.y + b2v;
    const float sc2b = acc23b.x + b2v, sc3b = acc23b.y + b2v;

    // ---- remainder column j = 1024 (4 rows) ----
    if (tid < MID) {
        const float E = E4[((long)(tid >> 2) * JST + 1024) * 4 + (tid & 3)];
        const float4 F = Fq[tid];
        const float wm = W2[tid];
        tmp[0][tid] = wm * __builtin_amdgcn_rcpf(__builtin_fmaf(E, F.x, 1.f));
        tmp[1][tid] = wm * __builtin_amdgcn_rcpf(__builtin_fmaf(E, F.y, 1.f));
        tmp[2][tid] = wm * __builtin_amdgcn_rcpf(__builtin_fmaf(E, F.z, 1.f));
        tmp[3][tid] = wm * __builtin_amdgcn_rcpf(__builtin_fmaf(E, F.w, 1.f));
    }
    __syncthreads();
    if (wv < 4) {
        float v = tmp[wv][lane] + ((lane < MID - 64) ? tmp[wv][lane + 64] : 0.f);
        #pragma unroll
        for (int off = 32; off > 0; off >>= 1) v += __shfl_down(v, off);
        if (lane == 0) sc4sh[wv] = v + b2v;
    }
    __syncthreads();

    // ---- loss + row-max (both columns folded per thread) ----
    const int tg0 = target[i0], tg1 = target[i0 + 1];
    const int tg2 = target[i0 + 2], tg3 = target[i0 + 3];
    const int jb = tid + 512;
    float ls = fabsf(sc0a - ((tid == tg0) ? 1.f : 0.f))
             + fabsf(sc1a - ((tid == tg1) ? 1.f : 0.f))
             + fabsf(sc2a - ((tid == tg2) ? 1.f : 0.f))
             + fabsf(sc3a - ((tid == tg3) ? 1.f : 0.f))
             + fabsf(sc0b - ((jb == tg0) ? 1.f : 0.f))
             + fabsf(sc1b - ((jb == tg1) ? 1.f : 0.f))
             + fabsf(sc2b - ((jb == tg2) ? 1.f : 0.f))
             + fabsf(sc3b - ((jb == tg3) ? 1.f : 0.f));
    float4 mx = make_float4(fmaxf(sc0a, sc0b), fmaxf(sc1a, sc1b),
                            fmaxf(sc2a, sc2b), fmaxf(sc3a, sc3b));
    if (tid == 0) {
        ls += fabsf(sc4sh[0] - ((1024 == tg0) ? 1.f : 0.f))
            + fabsf(sc4sh[1] - ((1024 == tg1) ? 1.f : 0.f))
            + fabsf(sc4sh[2] - ((1024 == tg2) ? 1.f : 0.f))
            + fabsf(sc4sh[3] - ((1024 == tg3) ? 1.f : 0.f));
        mx.x = fmaxf(mx.x, sc4sh[0]);
        mx.y = fmaxf(mx.y, sc4sh[1]);
        mx.z = fmaxf(mx.z, sc4sh[2]);
        mx.w = fmaxf(mx.w, sc4sh[3]);
    }
    #pragma unroll
    for (int off = 32; off > 0; off >>= 1) {
        ls += __shfl_down(ls, off);
        mx.x = fmaxf(mx.x, __shfl_down(mx.x, off));
        mx.y = fmaxf(mx.y, __shfl_down(mx.y, off));
        mx.z = fmaxf(mx.z, __shfl_down(mx.z, off));
        mx.w = fmaxf(mx.w, __shfl_down(mx.w, off));
    }
    if (lane == 0) { redl[wv] = ls; redm[wv] = mx; }
    __syncthreads();
    if (tid == 0) {
        float L = 0.f;
        float4 M = make_float4(-1e30f, -1e30f, -1e30f, -1e30f);
        #pragma unroll
        for (int k = 0; k < 8; ++k) {
            L += redl[k];
            M.x = fmaxf(M.x, redm[k].x);
            M.y = fmaxf(M.y, redm[k].y);
            M.z = fmaxf(M.z, redm[k].z);
            M.w = fmaxf(M.w, redm[k].w);
        }
        atomicAdd(out, L * (1.0f / ((float)NN * (float)NP1)));
        bmax = M;
    }
    __syncthreads();
    const float4 rm = bmax;

    // ---- exp + sum per row (both columns) ----
    const float e0a = __builtin_amdgcn_exp2f((sc0a - rm.x) * L2E);
    const float e1a = __builtin_amdgcn_exp2f((sc1a - rm.y) * L2E);
    const float e2a = __builtin_amdgcn_exp2f((sc2a - rm.z) * L2E);
    const float e3a = __builtin_amdgcn_exp2f((sc3a - rm.w) * L2E);
    const float e0b = __builtin_amdgcn_exp2f((sc0b - rm.x) * L2E);
    const float e1b = __builtin_amdgcn_exp2f((sc1b - rm.y) * L2E);
    const float e2b = __builtin_amdgcn_exp2f((sc2b - rm.z) * L2E);
    const float e3b = __builtin_amdgcn_exp2f((sc3b - rm.w) * L2E);
    float4 e4v = make_float4(0.f, 0.f, 0.f, 0.f);
    if (tid == 0) {
        e4v.x = __builtin_amdgcn_exp2f((sc4sh[0] - rm.x) * L2E);
        e4v.y = __builtin_amdgcn_exp2f((sc4sh[1] - rm.y) * L2E);
        e4v.z = __builtin_amdgcn_exp2f((sc4sh[2] - rm.z) * L2E);
        e4v.w = __builtin_amdgcn_exp2f((sc4sh[3] - rm.w) * L2E);
    }
    float4 es = make_float4(e0a + e0b + e4v.x, e1a + e1b + e4v.y,
                            e2a + e2b + e4v.z, e3a + e3b + e4v.w);
    #pragma unroll
    for (int off = 32; off > 0; off >>= 1) {
        es.x += __shfl_down(es.x, off);
        es.y += __shfl_down(es.y, off);
        es.z += __shfl_down(es.z, off);
        es.w += __shfl_down(es.w, off);
    }
    if (lane == 0) rede[wv] = es;
    __syncthreads();
    if (tid == 0) {
        float4 S = make_float4(0.f, 0.f, 0.f, 0.f);
        #pragma unroll
        for (int k = 0; k < 8; ++k) {
            S.x += rede[k].x; S.y += rede[k].y;
            S.z += rede[k].z; S.w += rede[k].w;
        }
        binv = make_float4(1.f / S.x, 1.f / S.y, 1.f / S.z, 1.f / S.w);
    }
    __syncthreads();
    const float4 iv = binv;

    // ---- write softmax rows (both columns) ----
    float* o0 = out + 1 + (long)(i0 + 0) * NP1;
    float* o1 = out + 1 + (long)(i0 + 1) * NP1;
    float* o2 = out + 1 + (long)(i0 + 2) * NP1;
    float* o3 = out + 1 + (long)(i0 + 3) * NP1;
    o0[tid] = e0a * iv.x;
    o1[tid] = e1a * iv.y;
    o2[tid] = e2a * iv.z;
    o3[tid] = e3a * iv.w;
    o0[jb] = e0b * iv.x;
    o1[jb] = e1b * iv.y;
    o2[jb] = e2b * iv.z;
    o3[jb] = e3b * iv.w;
    if (tid == 0) {
        o0[1024] = e4v.x * iv.x;
        o1[1024] = e4v.y * iv.y;
        o2[1024] = e4v.z * iv.z;
        o3[1024] = e4v.w * iv.w;
    }
    #undef QBODY
    #undef QCOL
    #undef LDXA
    #undef LDXB
}

extern "C" void kernel_launch(void* const* d_in, const int* in_sizes, int n_in,
                              void* d_out, int out_size, void* d_ws, size_t ws_size,
                              hipStream_t stream) {
    const float* sentence = (const float*)d_in[0];
    const int*   target   = (const int*)  d_in[1];
    const float* W1       = (const float*)d_in[2];
    const float* b1       = (const float*)d_in[3];
    const float* W2       = (const float*)d_in[4];
    const float* b2       = (const float*)d_in[5];
    float* out = (float*)d_out;
    float* E4  = (float*)d_ws;                 // 25*1088*4 floats (s1b eliminated)

    void* args[] = {
        (void*)&sentence, (void*)&W1, (void*)&b1, (void*)&W2,
        (void*)&b2, (void*)&target, (void*)&E4, (void*)&out
    };
    hipLaunchCooperativeKernel((const void*)fused_kernel,
                               dim3(NN / 4), dim3(512), args, 0, stream);
}

// Round 4
// 92.324 us; speedup vs baseline: 1.3878x; 1.3878x over previous
//
#include <hip/hip_runtime.h>

#define H     300
#define MID   100
#define NN    1024
#define NP1   1025
#define JST   1088   // padded j-extent of E4 (E4[25][1088][4] floats)

typedef float v2f __attribute__((ext_vector_type(2)));
static __device__ __forceinline__ v2f sp2(float s) { return (v2f){s, s}; }
static __device__ __forceinline__ v2f fma2(v2f a, v2f b, v2f c) {
    return __builtin_elementwise_fma(a, b, c);
}

// 16-lane-row rotate-add via DPP (VALU pipe, no DS traffic).
template <int CTRL>
static __device__ __forceinline__ float row_ror_add(float v) {
    const int s = __builtin_amdgcn_update_dpp(0, __float_as_int(v), CTRL, 0xF, 0xF, true);
    return v + __int_as_float(s);
}
// lane ^ 16 exchange-add (single DS-pipe swizzle, stays within 32-lane group)
static __device__ __forceinline__ float swz_xor16_add(float v) {
    const int s = __builtin_amdgcn_ds_swizzle(__float_as_int(v), 0x401F);
    return v + __int_as_float(s);
}
// full 32-lane-group sum: 1 ds_swizzle + 4 DPP row_ror adds
static __device__ __forceinline__ float red32(float v) {
    v = swz_xor16_add(v);
    v = row_ror_add<0x128>(v);   // row_ror:8
    v = row_ror_add<0x124>(v);   // row_ror:4
    v = row_ror_add<0x122>(v);   // row_ror:2
    v = row_ror_add<0x121>(v);   // row_ror:1
    return v;
}

// ---------------------------------------------------------------------------
// Kernel A (round-2 structure, now stores F = exp2(-s1*log2e) instead of s1):
// 512 blocks x 512 threads; block b -> items iA=2b, iB=2b+1. 8 waves; wave ->
// (half = wv&1, m-range mb = (wv>>1)*25). Sentence values in REGISTERS.
// Reduction = 1 ds_swizzle + 4 DPP adds. VGPR ~44, no LDS -> 4 blocks/CU.
// half==0 -> Fg[i*MID+m] (B consumes directly, no exp in B's setup).
// half==1 -> E4[m>>2][j][m&3] = exp2(-s2*log2e)  (j = item+1).
// ---------------------------------------------------------------------------
__global__ __launch_bounds__(512, 4) void precompute_kernel(
    const float* __restrict__ sentence,
    const float* __restrict__ W1,
    const float* __restrict__ b1,
    float* __restrict__ Fg,
    float* __restrict__ E4,
    float* __restrict__ out)
{
    const int tid = threadIdx.x;
    const int iA = blockIdx.x * 2, iB = iA + 1;
    const float NL = -1.4426950408889634f;

    if (blockIdx.x == 0) {
        if (tid == 0) out[0] = 0.0f;                              // loss accumulator
        if (tid < MID)
            E4[(long)((tid >> 2) * JST) * 4 + (tid & 3)] = 1.0f;  // j=0 column
    }

    const int lane = tid & 63;
    const int wv   = tid >> 6;        // 0..7
    const int sub  = lane >> 5;       // 0/1: which m within the step
    const int hb   = lane & 31;       // h-lane within the 32-group
    const int half = wv & 1;          // W1 half (s1 vs s2)
    const int mb   = (wv >> 1) * 25;  // m-range base: 0,25,50,75

    // Loop-invariant sentence values -> registers (coalesced 128B group reads)
    const float* sA = sentence + (long)iA * H + hb;
    const float* sB = sentence + (long)iB * H + hb;
    float ra[9], rb[9];
    #pragma unroll
    for (int k = 0; k < 9; ++k) { ra[k] = sA[32 * k]; rb[k] = sB[32 * k]; }
    const bool tl = hb < 12;                       // tail lanes (h = 288+hb < 300)
    const float ra9 = tl ? sA[288] : 0.0f;         // predicated load (OOB-safe)
    const float rb9 = tl ? sB[288] : 0.0f;
    const int h9 = 288 + (tl ? hb : 0);            // clamped tail index (in-bounds)

    for (int q = 0; q < 13; ++q) {
        const int off = 2 * q + sub;
        const int m   = mb + (off < 25 ? off : 24);      // clamp keeps loads in-bounds
        const float* wrow = W1 + (long)m * (2 * H) + half * H;

        float aA, aB;
        {
            const float w0 = wrow[hb];
            aA = w0 * ra[0];
            aB = w0 * rb[0];
        }
        #pragma unroll
        for (int k = 1; k < 9; ++k) {
            const float w = wrow[hb + 32 * k];
            aA = __builtin_fmaf(w, ra[k], aA);
            aB = __builtin_fmaf(w, rb[k], aB);
        }
        {
            const float w9 = wrow[h9];                   // ra9/rb9 zeroed for non-tail lanes
            aA = __builtin_fmaf(w9, ra9, aA);
            aB = __builtin_fmaf(w9, rb9, aB);
        }

        aA = red32(aA);
        aB = red32(aB);

        if (hb == 0 && off < 25) {
            if (half == 0) {
                const float bb = b1[m];
                Fg[iA * MID + m] = __builtin_amdgcn_exp2f((aA + bb) * NL);
                Fg[iB * MID + m] = __builtin_amdgcn_exp2f((aB + bb) * NL);
            } else {
                float* base = E4 + (long)((m >> 2) * JST) * 4 + (m & 3);
                base[(long)(iA + 1) * 4] = __builtin_amdgcn_exp2f(aA * NL);
                base[(long)(iB + 1) * 4] = __builtin_amdgcn_exp2f(aB * NL);
            }
        }
    }
}

// ---------------------------------------------------------------------------
// Kernel B: 512 blocks x 512 threads, __launch_bounds__(512,4) -> 2 blocks/CU
// (4 waves/SIMD, 2x the wave count of all previous rounds — the fused-kernel
// profile showed VALUBusy 25% / Occupancy 18% = latency-bound at 1 block/CU).
// Block handles 2 rows i0,i0+1; thread handles cols jA=tid, jB=tid+512.
// sigmoid(s1+x) = 1/(1+E*F): E from E4 (coalesced float4/quad), F from LDS
// (v2f per m = {row0,row1}). Rows packed as v2f so VALU lowers to v_pk_*:
//   w0/A+w1/B+w2/C+w3/D = [fma(w0,B,w1*A)*CD + fma(w2,D,w3*C)*AB] * rcp(ABCD)
// ---------------------------------------------------------------------------
__global__ __launch_bounds__(512, 4) void main_kernel(
    const float* __restrict__ Fg,
    const float* __restrict__ E4,
    const float* __restrict__ W2,
    const float* __restrict__ b2,
    const int*   __restrict__ target,
    float* __restrict__ out)
{
    __shared__ v2f    Fq2[MID];         // {F_row0, F_row1}[m]
    __shared__ float4 w4sh[MID / 4];    // W2 m-quads
    __shared__ float  tmp[2][104];      // remainder-column partials per row
    __shared__ float  redl[8];
    __shared__ v2f    redm[8];
    __shared__ v2f    rede[8];
    __shared__ float  sc4sh[2];
    __shared__ v2f    bmax2, binv2;

    const int i0  = blockIdx.x * 2;
    const int tid = threadIdx.x;
    const int lane = tid & 63, wv = tid >> 6;
    const float L2E = 1.4426950408889634f;
    const v2f one2 = sp2(1.0f);

    if (tid < MID) {
        Fq2[tid] = (v2f){Fg[(i0 + 0) * MID + tid], Fg[(i0 + 1) * MID + tid]};
    } else if (tid >= 128 && tid < 128 + MID / 4) {
        const int p = tid - 128;
        w4sh[p] = make_float4(W2[4 * p], W2[4 * p + 1], W2[4 * p + 2], W2[4 * p + 3]);
    }
    const float b2v = b2[0];
    __syncthreads();

    // coalesced: column j reads float4 at E4 + (p*JST + j)*4
    #define LDXA(p_) (*(const float4*)(E4 + ((long)(p_) * JST + tid) * 4))
    #define LDXB(p_) (*(const float4*)(E4 + ((long)(p_) * JST + tid + 512) * 4))

    v2f acca = sp2(0.f);    // {row0,row1} for col A
    v2f accb = sp2(0.f);    // {row0,row1} for col B

    #define QCOL(X, acc)                                                      \
        do {                                                                  \
            const v2f A = fma2(sp2((X).x), F0, one2);                         \
            const v2f B = fma2(sp2((X).y), F1, one2);                         \
            const v2f C = fma2(sp2((X).z), F2, one2);                         \
            const v2f D = fma2(sp2((X).w), F3, one2);                         \
            const v2f AB = A * B, CD = C * D, P = AB * CD;                    \
            const v2f R = {__builtin_amdgcn_rcpf(P.x),                        \
                           __builtin_amdgcn_rcpf(P.y)};                       \
            const v2f n1 = fma2(w0, B, w1 * A);                               \
            const v2f n2 = fma2(w2v, D, w3 * C);                              \
            acc = fma2(fma2(n1, CD, n2 * AB), R, acc);                        \
        } while (0)

    #define QBODY(p_, XA, XB)                                                 \
        do {                                                                  \
            const v2f F0 = Fq2[4 * (p_)];                                     \
            const v2f F1 = Fq2[4 * (p_) + 1];                                 \
            const v2f F2 = Fq2[4 * (p_) + 2];                                 \
            const v2f F3 = Fq2[4 * (p_) + 3];                                 \
            const float4 w = w4sh[p_];                                        \
            const v2f w0 = sp2(w.x), w1 = sp2(w.y);                           \
            const v2f w2v = sp2(w.z), w3 = sp2(w.w);                          \
            QCOL(XA, acca);                                                   \
            QCOL(XB, accb);                                                   \
        } while (0)

    // 25 m-quads, distance-2 software pipeline on the float4 loads
    float4 xa0 = LDXA(0), xb0 = LDXB(0);
    float4 xa1 = LDXA(1), xb1 = LDXB(1);
    #pragma unroll 2
    for (int p = 0; p < 23; ++p) {
        const float4 xan = LDXA(p + 2), xbn = LDXB(p + 2);
        QBODY(p, xa0, xb0);
        xa0 = xa1; xa1 = xan;
        xb0 = xb1; xb1 = xbn;
    }
    QBODY(23, xa0, xb0);
    QBODY(24, xa1, xb1);

    const float sc0a = acca.x + b2v, sc1a = acca.y + b2v;   // col A, rows 0,1
    const float sc0b = accb.x + b2v, sc1b = accb.y + b2v;   // col B, rows 0,1

    // ---- remainder column j = 1024 (2 rows) ----
    if (tid < MID) {
        const float E = E4[((long)(tid >> 2) * JST + 1024) * 4 + (tid & 3)];
        const v2f F = Fq2[tid];
        const float wm = W2[tid];
        tmp[0][tid] = wm * __builtin_amdgcn_rcpf(__builtin_fmaf(E, F.x, 1.f));
        tmp[1][tid] = wm * __builtin_amdgcn_rcpf(__builtin_fmaf(E, F.y, 1.f));
    }
    __syncthreads();
    if (wv < 2) {
        float v = tmp[wv][lane] + ((lane < MID - 64) ? tmp[wv][lane + 64] : 0.f);
        #pragma unroll
        for (int off = 32; off > 0; off >>= 1) v += __shfl_down(v, off);
        if (lane == 0) sc4sh[wv] = v + b2v;
    }
    __syncthreads();

    // ---- loss + row-max (both columns folded per thread) ----
    const int tg0 = target[i0], tg1 = target[i0 + 1];
    const int jb = tid + 512;
    float ls = fabsf(sc0a - ((tid == tg0) ? 1.f : 0.f))
             + fabsf(sc1a - ((tid == tg1) ? 1.f : 0.f))
             + fabsf(sc0b - ((jb == tg0) ? 1.f : 0.f))
             + fabsf(sc1b - ((jb == tg1) ? 1.f : 0.f));
    v2f mx = {fmaxf(sc0a, sc0b), fmaxf(sc1a, sc1b)};
    if (tid == 0) {
        ls += fabsf(sc4sh[0] - ((1024 == tg0) ? 1.f : 0.f))
            + fabsf(sc4sh[1] - ((1024 == tg1) ? 1.f : 0.f));
        mx.x = fmaxf(mx.x, sc4sh[0]);
        mx.y = fmaxf(mx.y, sc4sh[1]);
    }
    #pragma unroll
    for (int off = 32; off > 0; off >>= 1) {
        ls += __shfl_down(ls, off);
        mx.x = fmaxf(mx.x, __shfl_down(mx.x, off));
        mx.y = fmaxf(mx.y, __shfl_down(mx.y, off));
    }
    if (lane == 0) { redl[wv] = ls; redm[wv] = mx; }
    __syncthreads();
    if (tid == 0) {
        float L = 0.f;
        v2f M = {-1e30f, -1e30f};
        #pragma unroll
        for (int k = 0; k < 8; ++k) {
            L += redl[k];
            M.x = fmaxf(M.x, redm[k].x);
            M.y = fmaxf(M.y, redm[k].y);
        }
        atomicAdd(out, L * (1.0f / ((float)NN * (float)NP1)));
        bmax2 = M;
    }
    __syncthreads();
    const v2f rm = bmax2;

    // ---- exp + sum per row (both columns) ----
    const float e0a = __builtin_amdgcn_exp2f((sc0a - rm.x) * L2E);
    const float e1a = __builtin_amdgcn_exp2f((sc1a - rm.y) * L2E);
    const float e0b = __builtin_amdgcn_exp2f((sc0b - rm.x) * L2E);
    const float e1b = __builtin_amdgcn_exp2f((sc1b - rm.y) * L2E);
    v2f e4v = sp2(0.f);
    if (tid == 0) {
        e4v.x = __builtin_amdgcn_exp2f((sc4sh[0] - rm.x) * L2E);
        e4v.y = __builtin_amdgcn_exp2f((sc4sh[1] - rm.y) * L2E);
    }
    v2f es = {e0a + e0b + e4v.x, e1a + e1b + e4v.y};
    #pragma unroll
    for (int off = 32; off > 0; off >>= 1) {
        es.x += __shfl_down(es.x, off);
        es.y += __shfl_down(es.y, off);
    }
    if (lane == 0) rede[wv] = es;
    __syncthreads();
    if (tid == 0) {
        v2f S = sp2(0.f);
        #pragma unroll
        for (int k = 0; k < 8; ++k) { S.x += rede[k].x; S.y += rede[k].y; }
        binv2 = (v2f){1.f / S.x, 1.f / S.y};
    }
    __syncthreads();
    const v2f iv = binv2;

    // ---- write softmax rows (both columns) ----
    float* o0 = out + 1 + (long)(i0 + 0) * NP1;
    float* o1 = out + 1 + (long)(i0 + 1) * NP1;
    o0[tid] = e0a * iv.x;
    o1[tid] = e1a * iv.y;
    o0[jb] = e0b * iv.x;
    o1[jb] = e1b * iv.y;
    if (tid == 0) {
        o0[1024] = e4v.x * iv.x;
        o1[1024] = e4v.y * iv.y;
    }
    #undef QBODY
    #undef QCOL
    #undef LDXA
    #undef LDXB
}

extern "C" void kernel_launch(void* const* d_in, const int* in_sizes, int n_in,
                              void* d_out, int out_size, void* d_ws, size_t ws_size,
                              hipStream_t stream) {
    const float* sentence = (const float*)d_in[0];
    const int*   target   = (const int*)  d_in[1];
    const float* W1       = (const float*)d_in[2];
    const float* b1       = (const float*)d_in[3];
    const float* W2       = (const float*)d_in[4];
    const float* b2       = (const float*)d_in[5];
    float* out = (float*)d_out;

    float* Fg = (float*)d_ws;                  // 1024*100 floats (F = exp(-s1))
    float* E4 = Fg + NN * MID;                 // 25*1088*4 floats

    precompute_kernel<<<NN / 2, 512, 0, stream>>>(sentence, W1, b1, Fg, E4, out);
    main_kernel<<<NN / 2, 512, 0, stream>>>(Fg, E4, W2, b2, target, out);
}

// Round 5
// 91.631 us; speedup vs baseline: 1.3983x; 1.0076x over previous
//
#include <hip/hip_runtime.h>

#define H     300
#define MID   100
#define NN    1024
#define NP1   1025
#define JST   1088   // padded j-extent of E4 (E4[25][1088][4] floats)

typedef float v2f __attribute__((ext_vector_type(2)));
static __device__ __forceinline__ v2f sp2(float s) { return (v2f){s, s}; }
static __device__ __forceinline__ v2f fma2(v2f a, v2f b, v2f c) {
    return __builtin_elementwise_fma(a, b, c);
}

// 16-lane-row rotate-add via DPP (VALU pipe, no DS traffic).
template <int CTRL>
static __device__ __forceinline__ float row_ror_add(float v) {
    const int s = __builtin_amdgcn_update_dpp(0, __float_as_int(v), CTRL, 0xF, 0xF, true);
    return v + __int_as_float(s);
}
// lane ^ 16 exchange-add (single DS-pipe swizzle, stays within 32-lane group)
static __device__ __forceinline__ float swz_xor16_add(float v) {
    const int s = __builtin_amdgcn_ds_swizzle(__float_as_int(v), 0x401F);
    return v + __int_as_float(s);
}
// full 32-lane-group sum: 1 ds_swizzle + 4 DPP row_ror adds
static __device__ __forceinline__ float red32(float v) {
    v = swz_xor16_add(v);
    v = row_ror_add<0x128>(v);   // row_ror:8
    v = row_ror_add<0x124>(v);   // row_ror:4
    v = row_ror_add<0x122>(v);   // row_ror:2
    v = row_ror_add<0x121>(v);   // row_ror:1
    return v;
}

// ---------------------------------------------------------------------------
// Kernel A: 512 blocks x 1024 threads; block b -> items iA=2b, iB=2b+1.
// 32 lane-groups of 32; step s gives group (m,half) pair p = s*32+grp
// (200 pairs, 7 steps — was 16 groups x 13 steps). Same per-CU load totals
// and load->FMA efficiency as round 4, but 32 waves/CU (was 16) and the
// per-thread serial chain halves: attacks the latency-bound signature
// (VALUBusy 26% / Occupancy 18%) seen in the round-3 fused profile.
// Dot partition / FMA order / reduction tree bit-identical -> absmax must
// stay exactly 7.629e-6.
// half==0 -> Fg[i*MID+m] = exp2(-s1*log2e); half==1 -> E4 column (j=item+1).
// ---------------------------------------------------------------------------
__global__ __launch_bounds__(1024, 8) void precompute_kernel(
    const float* __restrict__ sentence,
    const float* __restrict__ W1,
    const float* __restrict__ b1,
    float* __restrict__ Fg,
    float* __restrict__ E4,
    float* __restrict__ out)
{
    const int tid = threadIdx.x;
    const int iA = blockIdx.x * 2, iB = iA + 1;
    const float NL = -1.4426950408889634f;

    if (blockIdx.x == 0) {
        if (tid == 0) out[0] = 0.0f;                              // loss accumulator
        if (tid < MID)
            E4[(long)((tid >> 2) * JST) * 4 + (tid & 3)] = 1.0f;  // j=0 column
    }

    const int grp = tid >> 5;         // 0..31 (32-lane group)
    const int hb  = tid & 31;         // h-lane within the group

    // Loop-invariant sentence values -> registers (coalesced 128B group reads)
    const float* sA = sentence + (long)iA * H + hb;
    const float* sB = sentence + (long)iB * H + hb;
    float ra[9], rb[9];
    #pragma unroll
    for (int k = 0; k < 9; ++k) { ra[k] = sA[32 * k]; rb[k] = sB[32 * k]; }
    const bool tl = hb < 12;                       // tail lanes (h = 288+hb < 300)
    const float ra9 = tl ? sA[288] : 0.0f;         // predicated load (OOB-safe)
    const float rb9 = tl ? sB[288] : 0.0f;
    const int h9 = 288 + (tl ? hb : 0);            // clamped tail index (in-bounds)

    for (int s = 0; s < 7; ++s) {
        const int p  = s * 32 + grp;                     // 0..223
        const int pc = p < 200 ? p : 199;                // clamp keeps loads in-bounds
        const int m  = pc >> 1, half = pc & 1;
        const float* wrow = W1 + (long)m * (2 * H) + half * H;

        float aA, aB;
        {
            const float w0 = wrow[hb];
            aA = w0 * ra[0];
            aB = w0 * rb[0];
        }
        #pragma unroll
        for (int k = 1; k < 9; ++k) {
            const float w = wrow[hb + 32 * k];
            aA = __builtin_fmaf(w, ra[k], aA);
            aB = __builtin_fmaf(w, rb[k], aB);
        }
        {
            const float w9 = wrow[h9];                   // ra9/rb9 zeroed for non-tail lanes
            aA = __builtin_fmaf(w9, ra9, aA);
            aB = __builtin_fmaf(w9, rb9, aB);
        }

        aA = red32(aA);
        aB = red32(aB);

        if (hb == 0 && p < 200) {
            if (half == 0) {
                const float bb = b1[m];
                Fg[iA * MID + m] = __builtin_amdgcn_exp2f((aA + bb) * NL);
                Fg[iB * MID + m] = __builtin_amdgcn_exp2f((aB + bb) * NL);
            } else {
                float* base = E4 + (long)((m >> 2) * JST) * 4 + (m & 3);
                base[(long)(iA + 1) * 4] = __builtin_amdgcn_exp2f(aA * NL);
                base[(long)(iB + 1) * 4] = __builtin_amdgcn_exp2f(aB * NL);
            }
        }
    }
}

// ---------------------------------------------------------------------------
// Kernel B: unchanged from round 4 (512 blocks x 512 threads, 2 rows/block,
// 2 cols/thread, common-denominator quad-rcp, v_pk f32 pairs). Every B-side
// change (R1 DS-halving, R4 occupancy-doubling) has been neutral — B is a
// minor term; kept byte-identical to isolate A's contribution.
// ---------------------------------------------------------------------------
__global__ __launch_bounds__(512, 4) void main_kernel(
    const float* __restrict__ Fg,
    const float* __restrict__ E4,
    const float* __restrict__ W2,
    const float* __restrict__ b2,
    const int*   __restrict__ target,
    float* __restrict__ out)
{
    __shared__ v2f    Fq2[MID];         // {F_row0, F_row1}[m]
    __shared__ float4 w4sh[MID / 4];    // W2 m-quads
    __shared__ float  tmp[2][104];      // remainder-column partials per row
    __shared__ float  redl[8];
    __shared__ v2f    redm[8];
    __shared__ v2f    rede[8];
    __shared__ float  sc4sh[2];
    __shared__ v2f    bmax2, binv2;

    const int i0  = blockIdx.x * 2;
    const int tid = threadIdx.x;
    const int lane = tid & 63, wv = tid >> 6;
    const float L2E = 1.4426950408889634f;
    const v2f one2 = sp2(1.0f);

    if (tid < MID) {
        Fq2[tid] = (v2f){Fg[(i0 + 0) * MID + tid], Fg[(i0 + 1) * MID + tid]};
    } else if (tid >= 128 && tid < 128 + MID / 4) {
        const int p = tid - 128;
        w4sh[p] = make_float4(W2[4 * p], W2[4 * p + 1], W2[4 * p + 2], W2[4 * p + 3]);
    }
    const float b2v = b2[0];
    __syncthreads();

    // coalesced: column j reads float4 at E4 + (p*JST + j)*4
    #define LDXA(p_) (*(const float4*)(E4 + ((long)(p_) * JST + tid) * 4))
    #define LDXB(p_) (*(const float4*)(E4 + ((long)(p_) * JST + tid + 512) * 4))

    v2f acca = sp2(0.f);    // {row0,row1} for col A
    v2f accb = sp2(0.f);    // {row0,row1} for col B

    #define QCOL(X, acc)                                                      \
        do {                                                                  \
            const v2f A = fma2(sp2((X).x), F0, one2);                         \
            const v2f B = fma2(sp2((X).y), F1, one2);                         \
            const v2f C = fma2(sp2((X).z), F2, one2);                         \
            const v2f D = fma2(sp2((X).w), F3, one2);                         \
            const v2f AB = A * B, CD = C * D, P = AB * CD;                    \
            const v2f R = {__builtin_amdgcn_rcpf(P.x),                        \
                           __builtin_amdgcn_rcpf(P.y)};                       \
            const v2f n1 = fma2(w0, B, w1 * A);                               \
            const v2f n2 = fma2(w2v, D, w3 * C);                              \
            acc = fma2(fma2(n1, CD, n2 * AB), R, acc);                        \
        } while (0)

    #define QBODY(p_, XA, XB)                                                 \
        do {                                                                  \
            const v2f F0 = Fq2[4 * (p_)];                                     \
            const v2f F1 = Fq2[4 * (p_) + 1];                                 \
            const v2f F2 = Fq2[4 * (p_) + 2];                                 \
            const v2f F3 = Fq2[4 * (p_) + 3];                                 \
            const float4 w = w4sh[p_];                                        \
            const v2f w0 = sp2(w.x), w1 = sp2(w.y);                           \
            const v2f w2v = sp2(w.z), w3 = sp2(w.w);                          \
            QCOL(XA, acca);                                                   \
            QCOL(XB, accb);                                                   \
        } while (0)

    // 25 m-quads, distance-2 software pipeline on the float4 loads
    float4 xa0 = LDXA(0), xb0 = LDXB(0);
    float4 xa1 = LDXA(1), xb1 = LDXB(1);
    #pragma unroll 2
    for (int p = 0; p < 23; ++p) {
        const float4 xan = LDXA(p + 2), xbn = LDXB(p + 2);
        QBODY(p, xa0, xb0);
        xa0 = xa1; xa1 = xan;
        xb0 = xb1; xb1 = xbn;
    }
    QBODY(23, xa0, xb0);
    QBODY(24, xa1, xb1);

    const float sc0a = acca.x + b2v, sc1a = acca.y + b2v;   // col A, rows 0,1
    const float sc0b = accb.x + b2v, sc1b = accb.y + b2v;   // col B, rows 0,1

    // ---- remainder column j = 1024 (2 rows) ----
    if (tid < MID) {
        const float E = E4[((long)(tid >> 2) * JST + 1024) * 4 + (tid & 3)];
        const v2f F = Fq2[tid];
        const float wm = W2[tid];
        tmp[0][tid] = wm * __builtin_amdgcn_rcpf(__builtin_fmaf(E, F.x, 1.f));
        tmp[1][tid] = wm * __builtin_amdgcn_rcpf(__builtin_fmaf(E, F.y, 1.f));
    }
    __syncthreads();
    if (wv < 2) {
        float v = tmp[wv][lane] + ((lane < MID - 64) ? tmp[wv][lane + 64] : 0.f);
        #pragma unroll
        for (int off = 32; off > 0; off >>= 1) v += __shfl_down(v, off);
        if (lane == 0) sc4sh[wv] = v + b2v;
    }
    __syncthreads();

    // ---- loss + row-max (both columns folded per thread) ----
    const int tg0 = target[i0], tg1 = target[i0 + 1];
    const int jb = tid + 512;
    float ls = fabsf(sc0a - ((tid == tg0) ? 1.f : 0.f))
             + fabsf(sc1a - ((tid == tg1) ? 1.f : 0.f))
             + fabsf(sc0b - ((jb == tg0) ? 1.f : 0.f))
             + fabsf(sc1b - ((jb == tg1) ? 1.f : 0.f));
    v2f mx = {fmaxf(sc0a, sc0b), fmaxf(sc1a, sc1b)};
    if (tid == 0) {
        ls += fabsf(sc4sh[0] - ((1024 == tg0) ? 1.f : 0.f))
            + fabsf(sc4sh[1] - ((1024 == tg1) ? 1.f : 0.f));
        mx.x = fmaxf(mx.x, sc4sh[0]);
        mx.y = fmaxf(mx.y, sc4sh[1]);
    }
    #pragma unroll
    for (int off = 32; off > 0; off >>= 1) {
        ls += __shfl_down(ls, off);
        mx.x = fmaxf(mx.x, __shfl_down(mx.x, off));
        mx.y = fmaxf(mx.y, __shfl_down(mx.y, off));
    }
    if (lane == 0) { redl[wv] = ls; redm[wv] = mx; }
    __syncthreads();
    if (tid == 0) {
        float L = 0.f;
        v2f M = {-1e30f, -1e30f};
        #pragma unroll
        for (int k = 0; k < 8; ++k) {
            L += redl[k];
            M.x = fmaxf(M.x, redm[k].x);
            M.y = fmaxf(M.y, redm[k].y);
        }
        atomicAdd(out, L * (1.0f / ((float)NN * (float)NP1)));
        bmax2 = M;
    }
    __syncthreads();
    const v2f rm = bmax2;

    // ---- exp + sum per row (both columns) ----
    const float e0a = __builtin_amdgcn_exp2f((sc0a - rm.x) * L2E);
    const float e1a = __builtin_amdgcn_exp2f((sc1a - rm.y) * L2E);
    const float e0b = __builtin_amdgcn_exp2f((sc0b - rm.x) * L2E);
    const float e1b = __builtin_amdgcn_exp2f((sc1b - rm.y) * L2E);
    v2f e4v = sp2(0.f);
    if (tid == 0) {
        e4v.x = __builtin_amdgcn_exp2f((sc4sh[0] - rm.x) * L2E);
        e4v.y = __builtin_amdgcn_exp2f((sc4sh[1] - rm.y) * L2E);
    }
    v2f es = {e0a + e0b + e4v.x, e1a + e1b + e4v.y};
    #pragma unroll
    for (int off = 32; off > 0; off >>= 1) {
        es.x += __shfl_down(es.x, off);
        es.y += __shfl_down(es.y, off);
    }
    if (lane == 0) rede[wv] = es;
    __syncthreads();
    if (tid == 0) {
        v2f S = sp2(0.f);
        #pragma unroll
        for (int k = 0; k < 8; ++k) { S.x += rede[k].x; S.y += rede[k].y; }
        binv2 = (v2f){1.f / S.x, 1.f / S.y};
    }
    __syncthreads();
    const v2f iv = binv2;

    // ---- write softmax rows (both columns) ----
    float* o0 = out + 1 + (long)(i0 + 0) * NP1;
    float* o1 = out + 1 + (long)(i0 + 1) * NP1;
    o0[tid] = e0a * iv.x;
    o1[tid] = e1a * iv.y;
    o0[jb] = e0b * iv.x;
    o1[jb] = e1b * iv.y;
    if (tid == 0) {
        o0[1024] = e4v.x * iv.x;
        o1[1024] = e4v.y * iv.y;
    }
    #undef QBODY
    #undef QCOL
    #undef LDXA
    #undef LDXB
}

extern "C" void kernel_launch(void* const* d_in, const int* in_sizes, int n_in,
                              void* d_out, int out_size, void* d_ws, size_t ws_size,
                              hipStream_t stream) {
    const float* sentence = (const float*)d_in[0];
    const int*   target   = (const int*)  d_in[1];
    const float* W1       = (const float*)d_in[2];
    const float* b1       = (const float*)d_in[3];
    const float* W2       = (const float*)d_in[4];
    const float* b2       = (const float*)d_in[5];
    float* out = (float*)d_out;

    float* Fg = (float*)d_ws;                  // 1024*100 floats (F = exp(-s1))
    float* E4 = Fg + NN * MID;                 // 25*1088*4 floats

    precompute_kernel<<<NN / 2, 1024, 0, stream>>>(sentence, W1, b1, Fg, E4, out);
    main_kernel<<<NN / 2, 512, 0, stream>>>(Fg, E4, W2, b2, target, out);
}